// Round 7
// baseline (113.780 us; speedup 1.0000x reference)
//
#include <hip/hip_runtime.h>
#include <hip/hip_bf16.h>

typedef __attribute__((ext_vector_type(4))) float f32x4;
typedef __attribute__((ext_vector_type(8))) short bf16x8;
typedef __attribute__((ext_vector_type(4))) short bf16x4;   // 8 B

#define T_DIM 8192
#define B_DIM 16
#define F_DIM 32
#define L_DIM 16
#define NTAPS 10
#define O_DIM 128
#define M_TOTAL (T_DIM * B_DIM)

// workspace offsets (bytes)
#define W2F_OFF  0        // w2f frag-layout bf16: 10*8*64*8*2 = 81920
#define BIAS_OFF 81920    // bias2 fp32: 512

static __device__ __forceinline__ unsigned short f2bf(float f) {
    union { float f; unsigned int u; } v; v.f = f;
    unsigned int r = v.u + 0x7fffu + ((v.u >> 16) & 1u);   // RNE
    return (unsigned short)(r >> 16);
}

// ---------------------------------------------------------------------------
// Kernel AB (fused): per block (s,nt):
//   G[l,f] = sum_op em_w[l,op] * K[l,s,op,f]        (into LDS, 256 thr)
//   W2[o,s,f] = sum_l dec_w[o,l] * G[l,f]           (wave 0)
// w2f fragment layout:
//   w2f[((s*8+nt)*64+lane)*8+j] = bf16(W2[nt*16+(lane&15)][s][(lane>>4)*8+j])
// bias2[o] = dec_b[o] + sum_l dec_w[o,l]*em_b[l]    (block (0,0), tid 128..255)
// ---------------------------------------------------------------------------
__global__ __launch_bounds__(256) void build_w2_fused(
    const float* __restrict__ K, const float* __restrict__ em_w,
    const float* __restrict__ em_b, const float* __restrict__ dec_w,
    const float* __restrict__ dec_b, unsigned short* __restrict__ w2f,
    float* __restrict__ bias2)
{
    int s = blockIdx.x >> 3, nt = blockIdx.x & 7;
    int tid = threadIdx.x;

    __shared__ float Glds[16 * 32];
    #pragma unroll
    for (int rep = 0; rep < 2; ++rep) {
        int idx = rep * 256 + tid;
        int l = idx >> 5, f = idx & 31;
        const float* Kb = K + (size_t)(l * NTAPS + s) * 1024 + f;
        const float* em = em_w + l * 32;
        float g = 0.f;
        #pragma unroll
        for (int op = 0; op < 32; ++op) g += em[op] * Kb[op * 32];
        Glds[idx] = g;
    }
    __syncthreads();

    if (tid < 64) {
        int lane = tid;
        int lo = lane & 15, fb = (lane >> 4) * 8;
        int o = nt * 16 + lo;
        float acc[8] = {0.f,0.f,0.f,0.f,0.f,0.f,0.f,0.f};
        #pragma unroll
        for (int l = 0; l < 16; ++l) {
            float dw = dec_w[o * L_DIM + l];
            const float* g = Glds + l * 32 + fb;
            #pragma unroll
            for (int j = 0; j < 8; ++j) acc[j] += dw * g[j];
        }
        unsigned short o8[8];
        #pragma unroll
        for (int j = 0; j < 8; ++j) o8[j] = f2bf(acc[j]);
        *(bf16x8*)(w2f + ((size_t)(s * 8 + nt) * 64 + lane) * 8) = *(const bf16x8*)o8;
    }
    if (s == 0 && nt == 0 && tid >= 128 && tid < 128 + O_DIM) {
        int o = tid - 128;
        float b = dec_b[o];
        #pragma unroll
        for (int l = 0; l < 16; ++l) b += dec_w[o * L_DIM + l] * em_b[l];
        bias2[o] = b;
    }
}

// ---------------------------------------------------------------------------
// Main: fused convert + conv-as-shifted-GEMM. 1024 blocks x 256 threads
// (4 waves), one 128-row tile per block. Static LDS 11,520 B: x-tile of
// 144 rows x 80 B (fp32->bf16 inline; 16 zeroed front rows = causality).
// w2f frags stream from global (80 KB, L2-resident). Operands swapped
// (W2 = A) so C-frag rows = o -> contiguous f32x4 stores. Bias loaded in
// epilogue only (keeps live VGPRs low).
// ---------------------------------------------------------------------------
#define XROWS 144
#define XSTRIDE 80                       // bytes; stride 20 banks -> ~2-way

__global__ __launch_bounds__(256) void s4_main_kernel(
    const float* __restrict__ x, const unsigned short* __restrict__ w2f,
    const float* __restrict__ bias2, float* __restrict__ out)
{
    __shared__ char xlds[XROWS * XSTRIDE];

    int tid  = threadIdx.x;
    int lane = tid & 63, w = tid >> 6;
    int lo = lane & 15, g = lane >> 4;

    int Rb = blockIdx.x * 128;           // first out-row (r = b*8192 + t)
    int b  = Rb >> 13;
    int t0 = Rb & (T_DIM - 1);

    // stage x rows t0-16 .. t0+127 -> xlds rows 0..143, bf16, zero t<0
    #pragma unroll
    for (int rep = 0; rep < 5; ++rep) {
        int c = rep * 256 + tid;                 // 16B-fp32 chunk index
        if (c < XROWS * 8) {
            int i = c >> 3, part = c & 7;
            int t = t0 + i - 16;
            unsigned short r4[4] = {0, 0, 0, 0};
            if (t >= 0) {
                f32x4 v = *(const f32x4*)(x + ((size_t)t * B_DIM + b) * F_DIM + part * 4);
                #pragma unroll
                for (int j = 0; j < 4; ++j) r4[j] = f2bf(v[j]);
            }
            *(bf16x4*)(xlds + i * XSTRIDE + part * 8) = *(const bf16x4*)r4;
        }
    }
    __syncthreads();

    f32x4 acc[2][8];
    #pragma unroll
    for (int mt = 0; mt < 2; ++mt)
        #pragma unroll
        for (int nt = 0; nt < 8; ++nt)
            acc[mt][nt] = (f32x4){0.f, 0.f, 0.f, 0.f};

    int ib = 16 + w * 32 + lo;   // xlds row for (mt=0, s=0)
    for (int s = 0; s < NTAPS; ++s) {
        bf16x8 wf[8];
        const bf16x8* wp = (const bf16x8*)w2f + (size_t)s * 8 * 64 + lane;
        #pragma unroll
        for (int nt = 0; nt < 8; ++nt) wf[nt] = wp[nt * 64];
        #pragma unroll
        for (int mt = 0; mt < 2; ++mt) {
            bf16x8 xf = *(const bf16x8*)(xlds + (ib + mt * 16 - s) * XSTRIDE + g * 16);
            #pragma unroll
            for (int nt = 0; nt < 8; ++nt)
                acc[mt][nt] = __builtin_amdgcn_mfma_f32_16x16x32_bf16(
                    wf[nt], xf, acc[mt][nt], 0, 0, 0);
        }
    }

    // epilogue: C-frag (swapped) col=lane&15=row-in-tile, row=(lane>>4)*4+j=o
    #pragma unroll
    for (int nt = 0; nt < 8; ++nt) {
        f32x4 bi = *(const f32x4*)(bias2 + nt * 16 + g * 4);
        #pragma unroll
        for (int mt = 0; mt < 2; ++mt) {
            size_t r = (size_t)Rb + w * 32 + mt * 16 + lo;
            f32x4 v = acc[mt][nt] + bi;
            *(f32x4*)(out + r * O_DIM + nt * 16 + g * 4) = v;
        }
    }
}

extern "C" void kernel_launch(void* const* d_in, const int* in_sizes, int n_in,
                              void* d_out, int out_size, void* d_ws, size_t ws_size,
                              hipStream_t stream)
{
    const float* x     = (const float*)d_in[0];
    const float* K     = (const float*)d_in[1];
    const float* em_w  = (const float*)d_in[2];
    const float* em_b  = (const float*)d_in[3];
    const float* dec_w = (const float*)d_in[4];
    const float* dec_b = (const float*)d_in[5];
    float* out = (float*)d_out;

    unsigned short* w2f   = (unsigned short*)((char*)d_ws + W2F_OFF);
    float*          bias2 = (float*)((char*)d_ws + BIAS_OFF);

    hipLaunchKernelGGL(build_w2_fused, dim3(NTAPS * 8), dim3(256), 0, stream,
                       K, em_w, em_b, dec_w, dec_b, w2f, bias2);
    hipLaunchKernelGGL(s4_main_kernel, dim3(M_TOTAL / 128), dim3(256), 0, stream,
                       x, w2f, bias2, out);
}

// Round 8
// 108.216 us; speedup vs baseline: 1.0514x; 1.0514x over previous
//
#include <hip/hip_runtime.h>
#include <hip/hip_bf16.h>

typedef __attribute__((ext_vector_type(4))) float f32x4;
typedef __attribute__((ext_vector_type(8))) short bf16x8;
typedef __attribute__((ext_vector_type(4))) short bf16x4;   // 8 B

#define T_DIM 8192
#define B_DIM 16
#define F_DIM 32
#define L_DIM 16
#define NTAPS 10
#define O_DIM 128
#define M_TOTAL (T_DIM * B_DIM)

// workspace offsets (bytes)
#define W2F_OFF  0        // w2f frag-layout bf16: 10*8*64*8*2 = 81920
#define BIAS_OFF 81920    // bias2 fp32: 512

static __device__ __forceinline__ unsigned short f2bf(float f) {
    union { float f; unsigned int u; } v; v.f = f;
    unsigned int r = v.u + 0x7fffu + ((v.u >> 16) & 1u);   // RNE
    return (unsigned short)(r >> 16);
}

// ---------------------------------------------------------------------------
// Kernel AB (fused): per block (s,nt):
//   G[l,f] = sum_op em_w[l,op] * K[l,s,op,f]        (into LDS, 256 thr)
//   W2[o,s,f] = sum_l dec_w[o,l] * G[l,f]           (wave 0)
// w2f fragment layout:
//   w2f[((s*8+nt)*64+lane)*8+j] = bf16(W2[nt*16+(lane&15)][s][(lane>>4)*8+j])
// bias2[o] = dec_b[o] + sum_l dec_w[o,l]*em_b[l]    (block (0,0), tid 128..255)
// ---------------------------------------------------------------------------
__global__ __launch_bounds__(256) void build_w2_fused(
    const float* __restrict__ K, const float* __restrict__ em_w,
    const float* __restrict__ em_b, const float* __restrict__ dec_w,
    const float* __restrict__ dec_b, unsigned short* __restrict__ w2f,
    float* __restrict__ bias2)
{
    int s = blockIdx.x >> 3, nt = blockIdx.x & 7;
    int tid = threadIdx.x;

    __shared__ float Glds[16 * 32];
    #pragma unroll
    for (int rep = 0; rep < 2; ++rep) {
        int idx = rep * 256 + tid;
        int l = idx >> 5, f = idx & 31;
        const float* Kb = K + (size_t)(l * NTAPS + s) * 1024 + f;
        const float* em = em_w + l * 32;
        float g = 0.f;
        #pragma unroll
        for (int op = 0; op < 32; ++op) g += em[op] * Kb[op * 32];
        Glds[idx] = g;
    }
    __syncthreads();

    if (tid < 64) {
        int lane = tid;
        int lo = lane & 15, fb = (lane >> 4) * 8;
        int o = nt * 16 + lo;
        float acc[8] = {0.f,0.f,0.f,0.f,0.f,0.f,0.f,0.f};
        #pragma unroll
        for (int l = 0; l < 16; ++l) {
            float dw = dec_w[o * L_DIM + l];
            const float* g = Glds + l * 32 + fb;
            #pragma unroll
            for (int j = 0; j < 8; ++j) acc[j] += dw * g[j];
        }
        unsigned short o8[8];
        #pragma unroll
        for (int j = 0; j < 8; ++j) o8[j] = f2bf(acc[j]);
        *(bf16x8*)(w2f + ((size_t)(s * 8 + nt) * 64 + lane) * 8) = *(const bf16x8*)o8;
    }
    if (s == 0 && nt == 0 && tid >= 128 && tid < 128 + O_DIM) {
        int o = tid - 128;
        float b = dec_b[o];
        #pragma unroll
        for (int l = 0; l < 16; ++l) b += dec_w[o * L_DIM + l] * em_b[l];
        bias2[o] = b;
    }
}

// ---------------------------------------------------------------------------
// Main: fused convert + conv-as-shifted-GEMM. 512 blocks x 512 threads
// (8 waves), one 256-row tile per block (round-6 geometry, measured best).
// Static LDS 21,760 B: x-tile of 272 rows x 80 B (fp32->bf16 inline;
// 16 zeroed front rows = causality). w2f frags stream from global
// (80 KB, L2-resident; 512 blocks -> 41 MB L2 traffic). Operands swapped
// (W2 = A) so C-frag rows = o -> contiguous f32x4 stores. Bias loaded in
// epilogue only (keeps live VGPRs low).
// ---------------------------------------------------------------------------
#define XROWS 272
#define XSTRIDE 80                       // bytes; stride 20 banks -> ~2-way

__global__ __launch_bounds__(512) void s4_main_kernel(
    const float* __restrict__ x, const unsigned short* __restrict__ w2f,
    const float* __restrict__ bias2, float* __restrict__ out)
{
    __shared__ char xlds[XROWS * XSTRIDE];

    int tid  = threadIdx.x;
    int lane = tid & 63, w = tid >> 6;
    int lo = lane & 15, g = lane >> 4;

    int Rb = blockIdx.x * 256;           // first out-row (r = b*8192 + t)
    int b  = Rb >> 13;
    int t0 = Rb & (T_DIM - 1);

    // stage x rows t0-16 .. t0+255 -> xlds rows 0..271, bf16, zero t<0
    #pragma unroll
    for (int rep = 0; rep < 5; ++rep) {
        int c = rep * 512 + tid;                 // 16B-fp32 chunk index
        if (c < XROWS * 8) {
            int i = c >> 3, part = c & 7;
            int t = t0 + i - 16;
            unsigned short r4[4] = {0, 0, 0, 0};
            if (t >= 0) {
                f32x4 v = *(const f32x4*)(x + ((size_t)t * B_DIM + b) * F_DIM + part * 4);
                #pragma unroll
                for (int j = 0; j < 4; ++j) r4[j] = f2bf(v[j]);
            }
            *(bf16x4*)(xlds + i * XSTRIDE + part * 8) = *(const bf16x4*)r4;
        }
    }
    __syncthreads();

    f32x4 acc[2][8];
    #pragma unroll
    for (int mt = 0; mt < 2; ++mt)
        #pragma unroll
        for (int nt = 0; nt < 8; ++nt)
            acc[mt][nt] = (f32x4){0.f, 0.f, 0.f, 0.f};

    int ib = 16 + w * 32 + lo;   // xlds row for (mt=0, s=0)
    for (int s = 0; s < NTAPS; ++s) {
        bf16x8 wf[8];
        const bf16x8* wp = (const bf16x8*)w2f + (size_t)s * 8 * 64 + lane;
        #pragma unroll
        for (int nt = 0; nt < 8; ++nt) wf[nt] = wp[nt * 64];
        #pragma unroll
        for (int mt = 0; mt < 2; ++mt) {
            bf16x8 xf = *(const bf16x8*)(xlds + (ib + mt * 16 - s) * XSTRIDE + g * 16);
            #pragma unroll
            for (int nt = 0; nt < 8; ++nt)
                acc[mt][nt] = __builtin_amdgcn_mfma_f32_16x16x32_bf16(
                    wf[nt], xf, acc[mt][nt], 0, 0, 0);
        }
    }

    // epilogue: C-frag (swapped) col=lane&15=row-in-tile, row=(lane>>4)*4+j=o
    #pragma unroll
    for (int nt = 0; nt < 8; ++nt) {
        f32x4 bi = *(const f32x4*)(bias2 + nt * 16 + g * 4);
        #pragma unroll
        for (int mt = 0; mt < 2; ++mt) {
            size_t r = (size_t)Rb + w * 32 + mt * 16 + lo;
            f32x4 v = acc[mt][nt] + bi;
            *(f32x4*)(out + r * O_DIM + nt * 16 + g * 4) = v;
        }
    }
}

extern "C" void kernel_launch(void* const* d_in, const int* in_sizes, int n_in,
                              void* d_out, int out_size, void* d_ws, size_t ws_size,
                              hipStream_t stream)
{
    const float* x     = (const float*)d_in[0];
    const float* K     = (const float*)d_in[1];
    const float* em_w  = (const float*)d_in[2];
    const float* em_b  = (const float*)d_in[3];
    const float* dec_w = (const float*)d_in[4];
    const float* dec_b = (const float*)d_in[5];
    float* out = (float*)d_out;

    unsigned short* w2f   = (unsigned short*)((char*)d_ws + W2F_OFF);
    float*          bias2 = (float*)((char*)d_ws + BIAS_OFF);

    hipLaunchKernelGGL(build_w2_fused, dim3(NTAPS * 8), dim3(256), 0, stream,
                       K, em_w, em_b, dec_w, dec_b, w2f, bias2);
    hipLaunchKernelGGL(s4_main_kernel, dim3(M_TOTAL / 256), dim3(512), 0, stream,
                       x, w2f, bias2, out);
}